// Round 3
// baseline (113.664 us; speedup 1.0000x reference)
//
#include <hip/hip_runtime.h>
#include <hip/hip_bf16.h>

// Problem constants (B, N, S, D) from reference
#define B_SZ 64
#define N_Q 32
#define S_D 256
#define D_DIM 128
#define NB 4            // queries per in-batch workgroup

typedef __attribute__((ext_vector_type(8))) short bf16x8;
typedef __attribute__((ext_vector_type(4))) float f32x4;

static __device__ __forceinline__ unsigned short f2bf(float f) {
    __hip_bfloat16 h = __float2bfloat16(f);
    return *reinterpret_cast<unsigned short*>(&h);
}

// One fused streaming pass: fp32 -> bf16 for Q (256 blks), D (2048 blks), ND (2048 blks).
// All ranges are exact multiples of 256 threads x float4 -> no bounds checks.
__global__ __launch_bounds__(256) void cvt_all(const float* __restrict__ q,
                                               const float* __restrict__ dd,
                                               const float* __restrict__ nd,
                                               unsigned short* __restrict__ qb,
                                               unsigned short* __restrict__ db,
                                               unsigned short* __restrict__ ndb) {
    const int blk = blockIdx.x;
    const float* src;
    unsigned short* dst;
    int i;
    if (blk < 256)       { src = q;  dst = qb;  i = blk * 256 + threadIdx.x; }
    else if (blk < 2304) { src = dd; dst = db;  i = (blk - 256) * 256 + threadIdx.x; }
    else                 { src = nd; dst = ndb; i = (blk - 2304) * 256 + threadIdx.x; }
    float4 v = reinterpret_cast<const float4*>(src)[i];
    ushort4 o;
    o.x = f2bf(v.x); o.y = f2bf(v.y); o.z = f2bf(v.z); o.w = f2bf(v.w);
    reinterpret_cast<ushort4*>(dst)[i] = o;
}

// Doc-stationary MaxSim on bf16 (L2/L3-resident after cvt_all).
// idx < 1024: c = idx>>4 (in-batch doc), b-group = (idx&15)*4, 4 b's -> scores[b*65+c]
// idx >= 1024: b = idx-1024, neg doc of b -> scores[b*65+64]
// Wave w owns s-columns [w*64, w*64+64); doc slice (64s x 128k bf16) in 16 bf16x8 regs.
__global__ __launch_bounds__(256) void maxsim_kernel(const unsigned short* __restrict__ Qb,
                                                     const unsigned short* __restrict__ Db,
                                                     const unsigned short* __restrict__ Ndb,
                                                     float* __restrict__ scores) {
    const int idx = blockIdx.x;
    int b0, nb, ccol;
    const unsigned short* dptr;
    if (idx < 1024) {
        const int c = idx >> 4;
        b0 = (idx & 15) * NB; nb = NB; ccol = c;
        dptr = Db + (size_t)c * S_D * D_DIM;
    } else {
        b0 = idx - 1024; nb = 1; ccol = B_SZ;
        dptr = Ndb + (size_t)b0 * S_D * D_DIM;
    }

    const int tid  = threadIdx.x;
    const int wave = tid >> 6;
    const int lane = tid & 63;
    const int l15  = lane & 15;
    const int l4   = lane >> 4;         // 0..3
    const int s_base = wave * 64;

    // ---- one-time: doc slice -> registers (B-operand fragments) ----
    // B frag: B[k = l4*8 + j][n = l15] = doc[s][k], 16 contiguous bytes along k.
    bf16x8 Bf[4][4];                    // [kk][nt]
    #pragma unroll
    for (int kk = 0; kk < 4; ++kk) {
        const int k0 = kk * 32 + l4 * 8;
        #pragma unroll
        for (int nt = 0; nt < 4; ++nt) {
            const int s = s_base + nt * 16 + l15;
            Bf[kk][nt] = *reinterpret_cast<const bf16x8*>(dptr + (size_t)s * D_DIM + k0);
        }
    }

    __shared__ float wred[NB][4][N_Q];  // [bb][wave][n] row-max of wave's 64-col slice

    const int npairs = (nb + 1) >> 1;
    for (int g = 0; g < npairs; ++g) {
        const int bb0 = 2 * g;
        const int bb1 = (2 * g + 1 < nb) ? 2 * g + 1 : 2 * g;
        const unsigned short* qA = Qb + (size_t)(b0 + bb0) * N_Q * D_DIM;
        const unsigned short* qB = Qb + (size_t)(b0 + bb1) * N_Q * D_DIM;

        f32x4 acc[2][2][4] = {};        // [which b][mt][nt]
        #pragma unroll
        for (int kk = 0; kk < 4; ++kk) {
            const int k0 = kk * 32 + l4 * 8;
            // A frag: A[m = l15][k = l4*8 + j], rows mt*16 + l15
            bf16x8 aA0 = *reinterpret_cast<const bf16x8*>(qA + (size_t)l15 * D_DIM + k0);
            bf16x8 aA1 = *reinterpret_cast<const bf16x8*>(qA + (size_t)(16 + l15) * D_DIM + k0);
            bf16x8 aB0 = *reinterpret_cast<const bf16x8*>(qB + (size_t)l15 * D_DIM + k0);
            bf16x8 aB1 = *reinterpret_cast<const bf16x8*>(qB + (size_t)(16 + l15) * D_DIM + k0);
            #pragma unroll
            for (int nt = 0; nt < 4; ++nt) {
                acc[0][0][nt] = __builtin_amdgcn_mfma_f32_16x16x32_bf16(aA0, Bf[kk][nt], acc[0][0][nt], 0, 0, 0);
                acc[0][1][nt] = __builtin_amdgcn_mfma_f32_16x16x32_bf16(aA1, Bf[kk][nt], acc[0][1][nt], 0, 0, 0);
                acc[1][0][nt] = __builtin_amdgcn_mfma_f32_16x16x32_bf16(aB0, Bf[kk][nt], acc[1][0][nt], 0, 0, 0);
                acc[1][1][nt] = __builtin_amdgcn_mfma_f32_16x16x32_bf16(aB1, Bf[kk][nt], acc[1][1][nt], 0, 0, 0);
            }
        }

        // per-b reduction: max over this wave's 64 s-columns for each of 32 rows
        #pragma unroll
        for (int h = 0; h < 2; ++h) {
            const int bb = (h == 0) ? bb0 : bb1;
            #pragma unroll
            for (int mt = 0; mt < 2; ++mt) {
                #pragma unroll
                for (int reg = 0; reg < 4; ++reg) {
                    float m = fmaxf(fmaxf(acc[h][mt][0][reg], acc[h][mt][1][reg]),
                                    fmaxf(acc[h][mt][2][reg], acc[h][mt][3][reg]));
                    m = fmaxf(m, __shfl_xor(m, 1, 64));
                    m = fmaxf(m, __shfl_xor(m, 2, 64));
                    m = fmaxf(m, __shfl_xor(m, 4, 64));
                    m = fmaxf(m, __shfl_xor(m, 8, 64));
                    if (l15 == 0) wred[bb][wave][mt * 16 + l4 * 4 + reg] = m;
                }
            }
        }
    }
    __syncthreads();

    // final: max over 4 waves (=> all 256 s), sum over 32 rows, write score
    const int bb = tid >> 5;            // 0..7
    const int n  = tid & 31;
    if (bb < nb) {
        float m = fmaxf(fmaxf(wred[bb][0][n], wred[bb][1][n]),
                        fmaxf(wred[bb][2][n], wred[bb][3][n]));
        m += __shfl_xor(m, 1, 64);
        m += __shfl_xor(m, 2, 64);
        m += __shfl_xor(m, 4, 64);
        m += __shfl_xor(m, 8, 64);
        m += __shfl_xor(m, 16, 64);
        if (n == 0) scores[(size_t)(b0 + bb) * 65 + ccol] = m;
    }
}

static __device__ __forceinline__ float softplusf(float x) {
    return fmaxf(x, 0.0f) + log1pf(expf(-fabsf(x)));
}

__global__ __launch_bounds__(64) void loss_kernel(const float* __restrict__ scores,
                                                  float* __restrict__ out) {
    const int b = threadIdx.x;          // 64 threads = 1 wave
    const float* row = scores + b * 65;
    const float pos  = row[b];
    const float negq = row[64];
    float nib = -1e30f;
    #pragma unroll
    for (int c = 0; c < B_SZ; ++c) {
        float v = row[c] - ((c == b) ? 1000000.0f : 0.0f);
        nib = fmaxf(nib, v);
    }
    float t = softplusf(negq - pos) + softplusf(nib - pos);
    t += __shfl_xor(t, 1, 64);
    t += __shfl_xor(t, 2, 64);
    t += __shfl_xor(t, 4, 64);
    t += __shfl_xor(t, 8, 64);
    t += __shfl_xor(t, 16, 64);
    t += __shfl_xor(t, 32, 64);
    if (b == 0) out[0] = t * (0.5f / 64.0f);
}

extern "C" void kernel_launch(void* const* d_in, const int* in_sizes, int n_in,
                              void* d_out, int out_size, void* d_ws, size_t ws_size,
                              hipStream_t stream) {
    const float* q  = (const float*)d_in[0];   // (64, 32, 128)
    const float* dd = (const float*)d_in[1];   // (64, 256, 128)
    const float* nd = (const float*)d_in[2];   // (64, 256, 128)
    float* out = (float*)d_out;

    const int nQ = B_SZ * N_Q * D_DIM;         // 262144
    const int nD = B_SZ * S_D * D_DIM;         // 2097152

    // Workspace: qb | db | ndb (bf16) | scores (64*65 fp32)
    unsigned short* qb  = (unsigned short*)d_ws;
    unsigned short* db  = qb + nQ;
    unsigned short* ndb = db + nD;
    float* scores = (float*)(ndb + nD);

    cvt_all<<<256 + 2048 + 2048, 256, 0, stream>>>(q, dd, nd, qb, db, ndb);

    maxsim_kernel<<<1024 + B_SZ, 256, 0, stream>>>(qb, db, ndb, scores);

    loss_kernel<<<1, 64, 0, stream>>>(scores, out);
}

// Round 4
// 106.250 us; speedup vs baseline: 1.0698x; 1.0698x over previous
//
#include <hip/hip_runtime.h>
#include <hip/hip_bf16.h>

// Problem constants (B, N, S, D) from reference
#define B_SZ 64
#define N_Q 32
#define S_D 256
#define D_DIM 128
#define NB 4            // queries per in-batch workgroup

typedef __attribute__((ext_vector_type(8))) short bf16x8;
typedef __attribute__((ext_vector_type(4))) float f32x4;

static __device__ __forceinline__ unsigned short f2bf(float f) {
    __hip_bfloat16 h = __float2bfloat16(f);
    return *reinterpret_cast<unsigned short*>(&h);
}

// Fused fp32->bf16 convert + permute into MFMA fragment order.
//   DP[doc][w][kk][nt][lane][j]  (doc slice in B-fragment order; 32768 bf16/doc)
//      = doc[s = w*64 + nt*16 + (lane&15)][k = kk*32 + (lane>>4)*8 + j]
//   QP[b][kk][mt][lane][j]       (query in A-fragment order; 4096 bf16/query batch)
//      = q[b][m = mt*16 + (lane&15)][k = kk*32 + (lane>>4)*8 + j]
// Every WG: 16384 fp32 in (coalesced) -> LDS permute -> 16384 bf16 out (coalesced).
// Grid: blk<256: doc-half (doc = blk>>1 in [0,128), h = blk&1); blk in [256,272): q-group of 4 b's.
__global__ __launch_bounds__(256) void cvt_permute(const float* __restrict__ q,
                                                   const float* __restrict__ dd,
                                                   const float* __restrict__ nd,
                                                   unsigned short* __restrict__ DP,
                                                   unsigned short* __restrict__ QP) {
    __shared__ unsigned short lds[16384];
    const int blk = blockIdx.x;
    const int tid = threadIdx.x;

    const float* srcf;
    unsigned short* dstp;
    bool isQ;
    if (blk < 256) {
        const int doc = blk >> 1, h = blk & 1;
        srcf = ((doc < B_SZ) ? (dd + (size_t)doc * 32768)
                             : (nd + (size_t)(doc - B_SZ) * 32768)) + h * 16384;
        dstp = DP + (size_t)doc * 32768 + h * 16384;
        isQ = false;
    } else {
        const int qg = blk - 256;
        srcf = q + (size_t)qg * 16384;
        dstp = QP + (size_t)qg * 16384;
        isQ = true;
    }

    #pragma unroll
    for (int it = 0; it < 16; ++it) {
        const int f = it * 256 + tid;            // float4 index, 0..4095
        float4 v = reinterpret_cast<const float4*>(srcf)[f];
        const int e = f * 4;
        int ldsoff;
        if (isQ) {
            const int b_local = e >> 12, inner = e & 4095;
            const int m = inner >> 7, k = inner & 127;
            const int lane = ((k >> 3) & 3) * 16 + (m & 15);
            ldsoff = b_local * 4096 + ((k >> 5) * 2 + (m >> 4)) * 512 + lane * 8 + (k & 7);
        } else {
            const int s_local = e >> 7, k = e & 127;
            const int lane = ((k >> 3) & 3) * 16 + (s_local & 15);
            ldsoff = ((s_local >> 6) * 16 + (k >> 5) * 4 + ((s_local >> 4) & 3)) * 512
                     + lane * 8 + (k & 7);
        }
        ushort4 o;
        o.x = f2bf(v.x); o.y = f2bf(v.y); o.z = f2bf(v.z); o.w = f2bf(v.w);
        *reinterpret_cast<ushort4*>(&lds[ldsoff]) = o;
    }
    __syncthreads();
    #pragma unroll
    for (int it = 0; it < 8; ++it) {
        const int o = it * 256 + tid;            // ushort8 index, 0..2047
        reinterpret_cast<bf16x8*>(dstp)[o] = reinterpret_cast<const bf16x8*>(lds)[o];
    }
}

// Doc-stationary MaxSim on permuted bf16 fragments — every global load is a
// contiguous 1 KB per wave; a wave's 16 doc loads span one contiguous 16 KB block.
// idx < 1024: c = idx>>4 (in-batch doc), b0 = (idx&15)*4, 4 b's -> scores[b*65+c]
// idx >= 1024: b = idx-1024, neg doc of b (DP slot 64+b)       -> scores[b*65+64]
__global__ __launch_bounds__(256) void maxsim_kernel(const unsigned short* __restrict__ QP,
                                                     const unsigned short* __restrict__ DP,
                                                     float* __restrict__ scores) {
    const int idx = blockIdx.x;
    int b0, nb, ccol, dcc;
    if (idx < 1024) {
        dcc = idx >> 4;
        b0 = (idx & 15) * NB; nb = NB; ccol = dcc;
    } else {
        b0 = idx - 1024; nb = 1; ccol = B_SZ; dcc = B_SZ + b0;
    }
    const unsigned short* dptr = DP + (size_t)dcc * 32768;

    const int tid  = threadIdx.x;
    const int wave = tid >> 6;
    const int lane = tid & 63;
    const int l15  = lane & 15;
    const int l4   = lane >> 4;

    // ---- one-time: doc slice -> registers (contiguous 16 KB per wave) ----
    bf16x8 Bf[4][4];                    // [kk][nt]
    #pragma unroll
    for (int kk = 0; kk < 4; ++kk) {
        #pragma unroll
        for (int nt = 0; nt < 4; ++nt) {
            Bf[kk][nt] = *reinterpret_cast<const bf16x8*>(
                dptr + wave * 8192 + kk * 2048 + nt * 512 + lane * 8);
        }
    }

    __shared__ float wred[NB][4][N_Q];  // [bb][wave][n] row-max of wave's 64-col slice

    const int npairs = (nb + 1) >> 1;
    for (int g = 0; g < npairs; ++g) {
        const int bb0 = 2 * g;
        const int bb1 = (2 * g + 1 < nb) ? 2 * g + 1 : 2 * g;
        const unsigned short* qA = QP + (size_t)(b0 + bb0) * 4096;
        const unsigned short* qB = QP + (size_t)(b0 + bb1) * 4096;

        f32x4 acc[2][2][4] = {};        // [which b][mt][nt]
        #pragma unroll
        for (int kk = 0; kk < 4; ++kk) {
            bf16x8 aA0 = *reinterpret_cast<const bf16x8*>(qA + kk * 1024 + lane * 8);
            bf16x8 aA1 = *reinterpret_cast<const bf16x8*>(qA + kk * 1024 + 512 + lane * 8);
            bf16x8 aB0 = *reinterpret_cast<const bf16x8*>(qB + kk * 1024 + lane * 8);
            bf16x8 aB1 = *reinterpret_cast<const bf16x8*>(qB + kk * 1024 + 512 + lane * 8);
            #pragma unroll
            for (int nt = 0; nt < 4; ++nt) {
                acc[0][0][nt] = __builtin_amdgcn_mfma_f32_16x16x32_bf16(aA0, Bf[kk][nt], acc[0][0][nt], 0, 0, 0);
                acc[0][1][nt] = __builtin_amdgcn_mfma_f32_16x16x32_bf16(aA1, Bf[kk][nt], acc[0][1][nt], 0, 0, 0);
                acc[1][0][nt] = __builtin_amdgcn_mfma_f32_16x16x32_bf16(aB0, Bf[kk][nt], acc[1][0][nt], 0, 0, 0);
                acc[1][1][nt] = __builtin_amdgcn_mfma_f32_16x16x32_bf16(aB1, Bf[kk][nt], acc[1][1][nt], 0, 0, 0);
            }
        }

        // per-b reduction: max over this wave's 64 s-columns for each of 32 rows
        #pragma unroll
        for (int h = 0; h < 2; ++h) {
            const int bb = (h == 0) ? bb0 : bb1;
            #pragma unroll
            for (int mt = 0; mt < 2; ++mt) {
                #pragma unroll
                for (int reg = 0; reg < 4; ++reg) {
                    float m = fmaxf(fmaxf(acc[h][mt][0][reg], acc[h][mt][1][reg]),
                                    fmaxf(acc[h][mt][2][reg], acc[h][mt][3][reg]));
                    m = fmaxf(m, __shfl_xor(m, 1, 64));
                    m = fmaxf(m, __shfl_xor(m, 2, 64));
                    m = fmaxf(m, __shfl_xor(m, 4, 64));
                    m = fmaxf(m, __shfl_xor(m, 8, 64));
                    if (l15 == 0) wred[bb][wave][mt * 16 + l4 * 4 + reg] = m;
                }
            }
        }
    }
    __syncthreads();

    // final: max over 4 waves (=> all 256 s), sum over 32 rows, write score
    const int bb = tid >> 5;            // 0..7
    const int n  = tid & 31;
    if (bb < nb) {
        float m = fmaxf(fmaxf(wred[bb][0][n], wred[bb][1][n]),
                        fmaxf(wred[bb][2][n], wred[bb][3][n]));
        m += __shfl_xor(m, 1, 64);
        m += __shfl_xor(m, 2, 64);
        m += __shfl_xor(m, 4, 64);
        m += __shfl_xor(m, 8, 64);
        m += __shfl_xor(m, 16, 64);
        if (n == 0) scores[(size_t)(b0 + bb) * 65 + ccol] = m;
    }
}

static __device__ __forceinline__ float softplusf(float x) {
    return fmaxf(x, 0.0f) + log1pf(expf(-fabsf(x)));
}

__global__ __launch_bounds__(64) void loss_kernel(const float* __restrict__ scores,
                                                  float* __restrict__ out) {
    const int b = threadIdx.x;          // 64 threads = 1 wave
    const float* row = scores + b * 65;
    const float pos  = row[b];
    const float negq = row[64];
    float nib = -1e30f;
    #pragma unroll
    for (int c = 0; c < B_SZ; ++c) {
        float v = row[c] - ((c == b) ? 1000000.0f : 0.0f);
        nib = fmaxf(nib, v);
    }
    float t = softplusf(negq - pos) + softplusf(nib - pos);
    t += __shfl_xor(t, 1, 64);
    t += __shfl_xor(t, 2, 64);
    t += __shfl_xor(t, 4, 64);
    t += __shfl_xor(t, 8, 64);
    t += __shfl_xor(t, 16, 64);
    t += __shfl_xor(t, 32, 64);
    if (b == 0) out[0] = t * (0.5f / 64.0f);
}

extern "C" void kernel_launch(void* const* d_in, const int* in_sizes, int n_in,
                              void* d_out, int out_size, void* d_ws, size_t ws_size,
                              hipStream_t stream) {
    const float* q  = (const float*)d_in[0];   // (64, 32, 128)
    const float* dd = (const float*)d_in[1];   // (64, 256, 128)
    const float* nd = (const float*)d_in[2];   // (64, 256, 128)
    float* out = (float*)d_out;

    // Workspace: DP (128 docs x 32768 bf16 = 8 MB) | QP (64 x 4096 bf16 = 512 KB) | scores
    unsigned short* DP = (unsigned short*)d_ws;
    unsigned short* QP = DP + (size_t)128 * 32768;
    float* scores = (float*)(QP + (size_t)64 * 4096);

    cvt_permute<<<272, 256, 0, stream>>>(q, dd, nd, DP, QP);

    maxsim_kernel<<<1024 + B_SZ, 256, 0, stream>>>(QP, DP, scores);

    loss_kernel<<<1, 64, 0, stream>>>(scores, out);
}

// Round 6
// 100.697 us; speedup vs baseline: 1.1288x; 1.0551x over previous
//
#include <hip/hip_runtime.h>
#include <hip/hip_bf16.h>

// Problem constants: B=64, N=32, S=256, D=128
#define B_SZ 64
#define N_Q 32

typedef __attribute__((ext_vector_type(8))) short bf16x8;
typedef __attribute__((ext_vector_type(4))) float f32x4;

static __device__ __forceinline__ unsigned short f2bf(float f) {
    __hip_bfloat16 h = __float2bfloat16(f);
    return *reinterpret_cast<unsigned short*>(&h);
}

// Load 8 consecutive fp32 (32 B), convert to one bf16x8 fragment.
static __device__ __forceinline__ bf16x8 cvt_frag(const float* __restrict__ src) {
    float4 a = reinterpret_cast<const float4*>(src)[0];
    float4 b = reinterpret_cast<const float4*>(src)[1];
    union { bf16x8 v; unsigned short u[8]; } t;
    t.u[0] = f2bf(a.x); t.u[1] = f2bf(a.y); t.u[2] = f2bf(a.z); t.u[3] = f2bf(a.w);
    t.u[4] = f2bf(b.x); t.u[5] = f2bf(b.y); t.u[6] = f2bf(b.z); t.u[7] = f2bf(b.w);
    return t.v;
}

#define MFMA(A, Bv, C) __builtin_amdgcn_mfma_f32_16x16x32_bf16(A, Bv, C, 0, 0, 0)

// Direct fp32 -> bf16 convert + permute into MFMA fragment order. No LDS.
// DP (ushort8 idx o): o = doc*4096 + w*1024 + kk*256 + nt*64 + ln
//    = doc[s = w*64 + nt*16 + (ln&15)][k = kk*32 + (ln>>4)*8 .. +7]   (doc 64..127 = nd)
// QP (ushort8 idx g): g = b*512 + kk*128 + mt*64 + ln
//    = q[b][n = mt*16 + (ln&15)][k = kk*32 + (ln>>4)*8 .. +7]
// Reads: per wave 16 consecutive rows x 128 contiguous B. Writes: perfectly coalesced 16 B.
__global__ __launch_bounds__(256) void cvt_permute(const float* __restrict__ q,
                                                   const float* __restrict__ dd,
                                                   const float* __restrict__ nd,
                                                   unsigned short* __restrict__ DP,
                                                   unsigned short* __restrict__ QP) {
    const int blk = blockIdx.x, tid = threadIdx.x;
    if (blk < 2048) {
        const int o = blk * 256 + tid;           // 0..524287
        const int doc = o >> 12;
        const int u = o & 4095;
        const int ln = u & 63, nt = (u >> 6) & 3, kk = (u >> 8) & 3, w = u >> 10;
        const int s  = w * 64 + nt * 16 + (ln & 15);
        const int k0 = kk * 32 + (ln >> 4) * 8;
        const float* src = ((doc < 64) ? (dd + (size_t)doc * 32768)
                                       : (nd + (size_t)(doc - 64) * 32768)) + s * 128 + k0;
        reinterpret_cast<bf16x8*>(DP)[o] = cvt_frag(src);
    } else {
        const int g = (blk - 2048) * 256 + tid;  // 0..32767
        const int b = g >> 9, u = g & 511;
        const int ln = u & 63, mt = (u >> 6) & 1, kk = u >> 7;
        const int n  = mt * 16 + (ln & 15);
        const int k0 = kk * 32 + (ln >> 4) * 8;
        reinterpret_cast<bf16x8*>(QP)[g] = cvt_frag(q + (size_t)b * 4096 + n * 128 + k0);
    }
}

// Doc-stationary MaxSim: doc slice staged in LDS (wave-private, no barrier),
// B fragments via ds_read_b128 (hidden under MFMA), A fragments from L2-hot QP.
// idx < 1024: c = idx>>4, b0 = (idx&15)*4, 4 b's -> scores[b*65+c]
// idx >= 1024: b = idx-1024, neg doc (slot 64+b) -> scores[b*65+64]
__global__ __launch_bounds__(256, 2) void maxsim_kernel(const unsigned short* __restrict__ QP,
                                                        const unsigned short* __restrict__ DP,
                                                        float* __restrict__ scores) {
    const int idx = blockIdx.x;
    int b0, nb, ccol, dcc;
    if (idx < 1024) {
        dcc = idx >> 4; b0 = (idx & 15) * 4; nb = 4; ccol = dcc;
    } else {
        b0 = idx - 1024; nb = 1; ccol = B_SZ; dcc = B_SZ + b0;
    }

    const int tid = threadIdx.x;
    const int wave = tid >> 6, lane = tid & 63;
    const int l15 = lane & 15, l4 = lane >> 4;

    __shared__ bf16x8 docB[4][16][64];   // [wave][kk*4+nt][lane] : 64 KiB
    __shared__ float wred[4][4][N_Q];    // [bb][wave][n]

    // ---- stage this wave's doc slice: 16 x (1 KiB contiguous global -> LDS) ----
    const bf16x8* dsrc = reinterpret_cast<const bf16x8*>(DP)
                         + (size_t)dcc * 4096 + wave * 1024 + lane;
    #pragma unroll
    for (int f = 0; f < 16; ++f)
        docB[wave][f][lane] = dsrc[f * 64];
    // wave-private staging: ds_write -> ds_read same wave, lgkmcnt handled by compiler

    const bf16x8* QP8 = reinterpret_cast<const bf16x8*>(QP);

    const int npairs = (nb + 1) >> 1;
    for (int g = 0; g < npairs; ++g) {
        const int bb0 = 2 * g;
        const int bb1 = (2 * g + 1 < nb) ? 2 * g + 1 : 2 * g;
        const bf16x8* qA = QP8 + (size_t)(b0 + bb0) * 512 + lane;
        const bf16x8* qB = QP8 + (size_t)(b0 + bb1) * 512 + lane;

        f32x4 acc[2][2][4] = {};         // [h][mt][nt]
        #pragma unroll
        for (int kk = 0; kk < 4; ++kk) {
            bf16x8 aA0 = qA[kk * 128];
            bf16x8 aA1 = qA[kk * 128 + 64];
            bf16x8 aB0 = qB[kk * 128];
            bf16x8 aB1 = qB[kk * 128 + 64];
            #pragma unroll
            for (int nt = 0; nt < 4; ++nt) {
                bf16x8 Bv = docB[wave][kk * 4 + nt][lane];
                acc[0][0][nt] = MFMA(aA0, Bv, acc[0][0][nt]);
                acc[0][1][nt] = MFMA(aA1, Bv, acc[0][1][nt]);
                acc[1][0][nt] = MFMA(aB0, Bv, acc[1][0][nt]);
                acc[1][1][nt] = MFMA(aB1, Bv, acc[1][1][nt]);
            }
        }

        // per-b: max over this wave's 64 s-columns for each of 32 rows
        #pragma unroll
        for (int h = 0; h < 2; ++h) {
            const int bb = (h == 0) ? bb0 : bb1;
            #pragma unroll
            for (int mt = 0; mt < 2; ++mt) {
                #pragma unroll
                for (int reg = 0; reg < 4; ++reg) {
                    float m = fmaxf(fmaxf(acc[h][mt][0][reg], acc[h][mt][1][reg]),
                                    fmaxf(acc[h][mt][2][reg], acc[h][mt][3][reg]));
                    m = fmaxf(m, __shfl_xor(m, 1, 64));
                    m = fmaxf(m, __shfl_xor(m, 2, 64));
                    m = fmaxf(m, __shfl_xor(m, 4, 64));
                    m = fmaxf(m, __shfl_xor(m, 8, 64));
                    if (l15 == 0) wred[bb][wave][mt * 16 + l4 * 4 + reg] = m;
                }
            }
        }
    }
    __syncthreads();

    // max over 4 waves (=> all 256 s), sum over 32 rows, write score
    const int bb = tid >> 5;             // 0..7
    const int n  = tid & 31;
    if (bb < nb) {
        float m = fmaxf(fmaxf(wred[bb][0][n], wred[bb][1][n]),
                        fmaxf(wred[bb][2][n], wred[bb][3][n]));
        m += __shfl_xor(m, 1, 64);
        m += __shfl_xor(m, 2, 64);
        m += __shfl_xor(m, 4, 64);
        m += __shfl_xor(m, 8, 64);
        m += __shfl_xor(m, 16, 64);
        if (n == 0) scores[(size_t)(b0 + bb) * 65 + ccol] = m;
    }
}

static __device__ __forceinline__ float softplusf(float x) {
    return fmaxf(x, 0.0f) + log1pf(expf(-fabsf(x)));
}

__global__ __launch_bounds__(64) void loss_kernel(const float* __restrict__ scores,
                                                  float* __restrict__ out) {
    const int b = threadIdx.x;           // 64 threads = 1 wave
    const float* row = scores + b * 65;
    const float pos  = row[b];
    const float negq = row[64];
    float nib = -1e30f;
    #pragma unroll
    for (int c = 0; c < B_SZ; ++c) {
        float v = row[c] - ((c == b) ? 1000000.0f : 0.0f);
        nib = fmaxf(nib, v);
    }
    float t = softplusf(negq - pos) + softplusf(nib - pos);
    t += __shfl_xor(t, 1, 64);
    t += __shfl_xor(t, 2, 64);
    t += __shfl_xor(t, 4, 64);
    t += __shfl_xor(t, 8, 64);
    t += __shfl_xor(t, 16, 64);
    t += __shfl_xor(t, 32, 64);
    if (b == 0) out[0] = t * (0.5f / 64.0f);
}

extern "C" void kernel_launch(void* const* d_in, const int* in_sizes, int n_in,
                              void* d_out, int out_size, void* d_ws, size_t ws_size,
                              hipStream_t stream) {
    const float* q  = (const float*)d_in[0];   // (64, 32, 128)
    const float* dd = (const float*)d_in[1];   // (64, 256, 128)
    const float* nd = (const float*)d_in[2];   // (64, 256, 128)
    float* out = (float*)d_out;

    // Workspace: DP (128 x 32768 bf16 = 8 MiB) | QP (64 x 4096 bf16 = 512 KiB) | scores
    unsigned short* DP = (unsigned short*)d_ws;
    unsigned short* QP = DP + (size_t)128 * 32768;
    float* scores = (float*)(QP + (size_t)64 * 4096);

    cvt_permute<<<2176, 256, 0, stream>>>(q, dd, nd, DP, QP);

    maxsim_kernel<<<1024 + B_SZ, 256, 0, stream>>>(QP, DP, scores);

    loss_kernel<<<1, 64, 0, stream>>>(scores, out);
}

// Round 7
// 88.179 us; speedup vs baseline: 1.2890x; 1.1420x over previous
//
#include <hip/hip_runtime.h>
#include <hip/hip_bf16.h>

// Problem constants: B=64, N=32, S=256, D=128
#define B_SZ 64
#define N_Q 32

typedef __attribute__((ext_vector_type(8))) short bf16x8;
typedef __attribute__((ext_vector_type(4))) float f32x4;

static __device__ __forceinline__ unsigned short f2bf(float f) {
    __hip_bfloat16 h = __float2bfloat16(f);
    return *reinterpret_cast<unsigned short*>(&h);
}

// Load 8 consecutive fp32 (32 B), convert to one bf16x8 fragment.
static __device__ __forceinline__ bf16x8 cvt_frag(const float* __restrict__ src) {
    float4 a = reinterpret_cast<const float4*>(src)[0];
    float4 b = reinterpret_cast<const float4*>(src)[1];
    union { bf16x8 v; unsigned short u[8]; } t;
    t.u[0] = f2bf(a.x); t.u[1] = f2bf(a.y); t.u[2] = f2bf(a.z); t.u[3] = f2bf(a.w);
    t.u[4] = f2bf(b.x); t.u[5] = f2bf(b.y); t.u[6] = f2bf(b.z); t.u[7] = f2bf(b.w);
    return t.v;
}

#define MFMA(A, Bv, C) __builtin_amdgcn_mfma_f32_16x16x32_bf16(A, Bv, C, 0, 0, 0)

// Direct fp32 -> bf16 convert + permute into MFMA fragment order. No LDS.
// DP (ushort8 idx o): o = doc*4096 + ch*1024 + kk*256 + nt*64 + ln
//    = doc[s = ch*64 + nt*16 + (ln&15)][k = kk*32 + (ln>>4)*8 .. +7]  (doc 64..127 = nd)
// QP (ushort8 idx g): g = b*512 + kk*128 + mt*64 + ln
//    = q[b][n = mt*16 + (ln&15)][k = kk*32 + (ln>>4)*8 .. +7]
__global__ __launch_bounds__(256) void cvt_permute(const float* __restrict__ q,
                                                   const float* __restrict__ dd,
                                                   const float* __restrict__ nd,
                                                   unsigned short* __restrict__ DP,
                                                   unsigned short* __restrict__ QP) {
    const int blk = blockIdx.x, tid = threadIdx.x;
    if (blk < 2048) {
        const int o = blk * 256 + tid;           // 0..524287
        const int doc = o >> 12;
        const int u = o & 4095;
        const int ln = u & 63, nt = (u >> 6) & 3, kk = (u >> 8) & 3, ch = u >> 10;
        const int s  = ch * 64 + nt * 16 + (ln & 15);
        const int k0 = kk * 32 + (ln >> 4) * 8;
        const float* src = ((doc < 64) ? (dd + (size_t)doc * 32768)
                                       : (nd + (size_t)(doc - 64) * 32768)) + s * 128 + k0;
        reinterpret_cast<bf16x8*>(DP)[o] = cvt_frag(src);
    } else {
        const int g = (blk - 2048) * 256 + tid;  // 0..32767
        const int b = g >> 9, u = g & 511;
        const int ln = u & 63, mt = (u >> 6) & 1, kk = u >> 7;
        const int n  = mt * 16 + (ln & 15);
        const int k0 = kk * 32 + (ln >> 4) * 8;
        reinterpret_cast<bf16x8*>(QP)[g] = cvt_frag(q + (size_t)b * 4096 + n * 128 + k0);
    }
}

// Query-per-wave MaxSim.
// wg < 1024: c = wg>>4, wave w handles query b = (wg&15)*4 + w over all 256 s.
// wg >= 1024: neg pair b = wg-1024 (doc slot 64+b); wave w handles s-chunk w only.
// Doc staged once in 64 KiB LDS (each wave stages its quarter); A fragments for the
// wave's query loaded in ONE batch into 32 VGPRs; compute loop has zero global loads.
__global__ __launch_bounds__(256, 2) void maxsim_kernel(const unsigned short* __restrict__ QP,
                                                        const unsigned short* __restrict__ DP,
                                                        float* __restrict__ scores) {
    const int wg  = blockIdx.x;
    const int tid = threadIdx.x;
    const int wave = tid >> 6, lane = tid & 63;
    const int l15 = lane & 15;

    __shared__ bf16x8 docB[4096];        // 64 KiB: [ch*1024 + kk*256 + nt*64 + lane]
    __shared__ float wredN[4][4][8];     // neg path: [wave][l4][mt*4+reg]

    const bf16x8* DP8 = reinterpret_cast<const bf16x8*>(DP);
    const bf16x8* QP8 = reinterpret_cast<const bf16x8*>(QP);

    int c, b;
    bool isNeg;
    if (wg < 1024) { c = wg >> 4; b = (wg & 15) * 4 + wave; isNeg = false; }
    else           { b = wg - 1024; c = b; isNeg = true; }
    const int dcc = isNeg ? (64 + b) : c;

    // ---- one batch: this wave's 8 A-fragments (A[kk][mt]) ----
    bf16x8 Af[4][2];
    const bf16x8* qsrc = QP8 + (size_t)b * 512 + lane;
    #pragma unroll
    for (int kk = 0; kk < 4; ++kk) {
        Af[kk][0] = qsrc[kk * 128];
        Af[kk][1] = qsrc[kk * 128 + 64];
    }

    // ---- stage this wave's doc quarter: 16 contiguous 1 KiB wave-loads ----
    const bf16x8* dsrc = DP8 + (size_t)dcc * 4096 + wave * 1024 + lane;
    #pragma unroll
    for (int f = 0; f < 16; ++f)
        docB[wave * 1024 + f * 64 + lane] = dsrc[f * 64];
    __syncthreads();

    // ---- compute: running per-lane row-max across s-chunks ----
    float rmax[2][4];
    #pragma unroll
    for (int mt = 0; mt < 2; ++mt)
        #pragma unroll
        for (int r = 0; r < 4; ++r) rmax[mt][r] = -3.0e38f;

    const int nch = isNeg ? 1 : 4;
    for (int i = 0; i < nch; ++i) {
        const int ch = isNeg ? wave : ((wave + i) & 3);
        f32x4 acc[2][4] = {};            // [mt][nt]
        #pragma unroll
        for (int kk = 0; kk < 4; ++kk) {
            #pragma unroll
            for (int nt = 0; nt < 4; ++nt) {
                bf16x8 Bv = docB[ch * 1024 + kk * 256 + nt * 64 + lane];
                acc[0][nt] = MFMA(Af[kk][0], Bv, acc[0][nt]);
                acc[1][nt] = MFMA(Af[kk][1], Bv, acc[1][nt]);
            }
        }
        #pragma unroll
        for (int mt = 0; mt < 2; ++mt)
            #pragma unroll
            for (int r = 0; r < 4; ++r)
                rmax[mt][r] = fmaxf(rmax[mt][r],
                    fmaxf(fmaxf(acc[mt][0][r], acc[mt][1][r]),
                          fmaxf(acc[mt][2][r], acc[mt][3][r])));
    }

    // ---- epilogue ----
    // Butterfly max over l15 (16 col-residues) -> row-max; then sum rows.
    float part = 0.0f;
    #pragma unroll
    for (int mt = 0; mt < 2; ++mt)
        #pragma unroll
        for (int r = 0; r < 4; ++r) {
            float m = rmax[mt][r];
            m = fmaxf(m, __shfl_xor(m, 1, 64));
            m = fmaxf(m, __shfl_xor(m, 2, 64));
            m = fmaxf(m, __shfl_xor(m, 4, 64));
            m = fmaxf(m, __shfl_xor(m, 8, 64));
            if (isNeg) {
                if (l15 == 0) wredN[wave][lane >> 4][mt * 4 + r] = m;
            } else {
                part += m;               // row n = mt*16 + (lane>>4)*4 + r
            }
        }
    if (!isNeg) {
        part += __shfl_xor(part, 16, 64);
        part += __shfl_xor(part, 32, 64);
        if (lane == 0) scores[(size_t)b * 65 + c] = part;
    } else {
        __syncthreads();                 // whole WG takes this branch (wg-uniform)
        if (tid < 32) {
            const int l4v = tid >> 3, slot = tid & 7;
            float m = fmaxf(fmaxf(wredN[0][l4v][slot], wredN[1][l4v][slot]),
                            fmaxf(wredN[2][l4v][slot], wredN[3][l4v][slot]));
            m += __shfl_xor(m, 1, 64);
            m += __shfl_xor(m, 2, 64);
            m += __shfl_xor(m, 4, 64);
            m += __shfl_xor(m, 8, 64);
            m += __shfl_xor(m, 16, 64);
            if (tid == 0) scores[(size_t)b * 65 + 64] = m;
        }
    }
}

static __device__ __forceinline__ float softplusf(float x) {
    return fmaxf(x, 0.0f) + log1pf(expf(-fabsf(x)));
}

__global__ __launch_bounds__(64) void loss_kernel(const float* __restrict__ scores,
                                                  float* __restrict__ out) {
    const int b = threadIdx.x;           // 64 threads = 1 wave
    const float* row = scores + b * 65;
    const float pos  = row[b];
    const float negq = row[64];
    float nib = -1e30f;
    #pragma unroll
    for (int c = 0; c < B_SZ; ++c) {
        float v = row[c] - ((c == b) ? 1000000.0f : 0.0f);
        nib = fmaxf(nib, v);
    }
    float t = softplusf(negq - pos) + softplusf(nib - pos);
    t += __shfl_xor(t, 1, 64);
    t += __shfl_xor(t, 2, 64);
    t += __shfl_xor(t, 4, 64);
    t += __shfl_xor(t, 8, 64);
    t += __shfl_xor(t, 16, 64);
    t += __shfl_xor(t, 32, 64);
    if (b == 0) out[0] = t * (0.5f / 64.0f);
}

extern "C" void kernel_launch(void* const* d_in, const int* in_sizes, int n_in,
                              void* d_out, int out_size, void* d_ws, size_t ws_size,
                              hipStream_t stream) {
    const float* q  = (const float*)d_in[0];   // (64, 32, 128)
    const float* dd = (const float*)d_in[1];   // (64, 256, 128)
    const float* nd = (const float*)d_in[2];   // (64, 256, 128)
    float* out = (float*)d_out;

    // Workspace: DP (128 x 4096 ushort8 = 8 MiB) | QP (64 x 512 ushort8 = 512 KiB) | scores
    unsigned short* DP = (unsigned short*)d_ws;
    unsigned short* QP = DP + (size_t)128 * 32768;
    float* scores = (float*)(QP + (size_t)64 * 4096);

    cvt_permute<<<2176, 256, 0, stream>>>(q, dd, nd, DP, QP);

    maxsim_kernel<<<1024 + B_SZ, 256, 0, stream>>>(QP, DP, scores);

    loss_kernel<<<1, 64, 0, stream>>>(scores, out);
}